// Round 4
// baseline (172.891 us; speedup 1.0000x reference)
//
#include <hip/hip_runtime.h>
#include <math.h>

#define BB 32
#define CC 256
#define NN 1024
#define THR 8.0f

typedef unsigned short u16;
typedef unsigned int u32;
typedef u16 u16x8 __attribute__((ext_vector_type(8)));
typedef _Float16 h16;
typedef h16 h16x2 __attribute__((ext_vector_type(2)));
typedef h16 h16x8 __attribute__((ext_vector_type(8)));
typedef float f32x4 __attribute__((ext_vector_type(4)));
typedef float f32x16 __attribute__((ext_vector_type(16)));
typedef u32 u32x4v __attribute__((ext_vector_type(4)));

__device__ __forceinline__ h16x8 ldh8(const u16* p) {
    return __builtin_bit_cast(h16x8, *(const u16x8*)p);
}
__device__ __forceinline__ f32x4 mfma16(h16x8 a, h16x8 b, f32x4 c) {
    return __builtin_amdgcn_mfma_f32_16x16x32_f16(a, b, c, 0, 0, 0);
}
__device__ __forceinline__ f32x16 mfma32(h16x8 a, h16x8 b, f32x16 c) {
    return __builtin_amdgcn_mfma_f32_32x32x16_f16(a, b, c, 0, 0, 0);
}
// async global->LDS, 16B per lane: HW dst = wave-uniform base + lane*16
__device__ __forceinline__ void gll16(const void* g, void* l) {
    __builtin_amdgcn_global_load_lds((const __attribute__((address_space(1))) u32*)g,
                                     (__attribute__((address_space(3))) u32*)l, 16, 0, 0);
}

// ---------------------------------------------------------------------------
// Kernel 1: blocks <2048: transpose x[b][c][p] f32 -> qf[b][p][c] fp16
//           blocks >=2048: W f32 -> fragment-major fp16 whf (merged k_wprep)
// ---------------------------------------------------------------------------
__global__ __launch_bounds__(256) void k_split(const float* __restrict__ x,
                                               u16* __restrict__ qf,
                                               const float* __restrict__ w,
                                               u16* __restrict__ whf) {
    __shared__ float lds[64][65];
    int bid = blockIdx.x;
    int t = threadIdx.x;
    if (bid >= 2048) {  // wprep: slot s=(ot*8+ks)*64+l; elem e: W[ot*16+(l&15)][ks*32+8*(l>>4)+e]
        int s = (bid - 2048) * 256 + t;
        int ot = s >> 9, ks = (s >> 6) & 7, l = s & 63;
        const float* src = w + (size_t)(ot * 16 + (l & 15)) * CC + ks * 32 + 8 * (l >> 4);
        float4 a = *(const float4*)src;
        float4 c = *(const float4*)(src + 4);
        u16x8 o;
        o[0] = __builtin_bit_cast(u16, (h16)a.x); o[1] = __builtin_bit_cast(u16, (h16)a.y);
        o[2] = __builtin_bit_cast(u16, (h16)a.z); o[3] = __builtin_bit_cast(u16, (h16)a.w);
        o[4] = __builtin_bit_cast(u16, (h16)c.x); o[5] = __builtin_bit_cast(u16, (h16)c.y);
        o[6] = __builtin_bit_cast(u16, (h16)c.z); o[7] = __builtin_bit_cast(u16, (h16)c.w);
        *(u16x8*)(whf + (size_t)s * 8) = o;
        return;
    }
    int b = bid >> 6, ct = (bid >> 4) & 3, pt = bid & 15;
    int c0 = ct * 64, p0 = pt * 64;
    const float* xb = x + ((size_t)b * CC + c0) * NN + p0;
#pragma unroll
    for (int it = 0; it < 4; ++it) {
        int cl = (t >> 4) + it * 16;
        int pl = (t & 15) * 4;
        float4 v = *(const float4*)(xb + (size_t)cl * NN + pl);
        lds[pl + 0][cl] = v.x;
        lds[pl + 1][cl] = v.y;
        lds[pl + 2][cl] = v.z;
        lds[pl + 3][cl] = v.w;
    }
    __syncthreads();
    u16* qb = qf + ((size_t)b * NN + p0) * CC + c0;
#pragma unroll
    for (int it = 0; it < 2; ++it) {
        int pl = (t >> 3) + it * 32;
        int cl = (t & 7) * 8;
        u16x8 hv;
#pragma unroll
        for (int e = 0; e < 8; ++e) hv[e] = __builtin_bit_cast(u16, (h16)lds[pl][cl + e]);
        *(u16x8*)(qb + (size_t)pl * CC + cl) = hv;
    }
}

// ---------------------------------------------------------------------------
// Kernel 2: V = W@X + b -> Vimg[b][jt 32][o 256][j 32] fp16 (LDS-image linear).
// 1024 blocks (b, pt in 0..31 = 32-p tiles), 4 waves x 64 o-channels.
// X-tile gll-staged into XOR-swizzled LDS; A-frags coalesced from whf.
// ---------------------------------------------------------------------------
__global__ __launch_bounds__(256, 4) void k_vgemm(const u16* __restrict__ qf,
                                                  const u16* __restrict__ whf,
                                                  const float* __restrict__ bias,
                                                  u16* __restrict__ vimg) {
    __shared__ __align__(16) u16 smem[10240];  // Xs [0,8192) swz; Vs wave*2560 [64][40]
    int bid = blockIdx.x;
    int b = bid >> 5, pt = bid & 31;
    int t = threadIdx.x, wave = t >> 6, lane = t & 63;
    int l15 = lane & 15, l4 = lane >> 4;
    int p0 = pt * 32, o0 = wave * 64;
    // stage Xs 32 rows x 256c, granule(16B) swizzle g^= row&7; src pre-swizzled
    {
        int Gb = wave * 256;
#pragma unroll
        for (int inst = 0; inst < 4; ++inst) {
            int G = Gb + inst * 64 + lane;
            int row = G >> 5, g = G & 31;
            gll16(qf + (size_t)(b * NN + p0 + row) * CC + ((g ^ (row & 7)) << 3),
                  smem + (size_t)(Gb + inst * 64) * 8);
        }
    }
    __syncthreads();
    f32x4 acc[4][2];
#pragma unroll
    for (int m = 0; m < 4; ++m)
#pragma unroll
        for (int n = 0; n < 2; ++n) acc[m][n] = (f32x4){0.f, 0.f, 0.f, 0.f};
#pragma unroll
    for (int ks = 0; ks < 8; ++ks) {
        h16x8 afr[4], bfr[2];
#pragma unroll
        for (int m = 0; m < 4; ++m)
            afr[m] = ldh8(whf + (size_t)(((wave * 4 + m) * 8 + ks) * 64 + lane) * 8);
#pragma unroll
        for (int n = 0; n < 2; ++n) {
            int row = n * 16 + l15;
            bfr[n] = ldh8(smem + row * 256 + (((4 * ks + l4) ^ (l15 & 7)) << 3));
        }
#pragma unroll
        for (int m = 0; m < 4; ++m)
#pragma unroll
            for (int n = 0; n < 2; ++n) acc[m][n] = mfma16(afr[m], bfr[n], acc[m][n]);
    }
    __syncthreads();  // all waves done reading Xs
    u16* Vs = smem + wave * 2560;  // [64][40]
#pragma unroll
    for (int m = 0; m < 4; ++m) {
#pragma unroll
        for (int r = 0; r < 4; ++r) {
            int ol = m * 16 + 4 * l4 + r;
            float bv = bias[o0 + ol];
#pragma unroll
            for (int n = 0; n < 2; ++n)
                Vs[ol * 40 + n * 16 + l15] =
                    __builtin_bit_cast(u16, (h16)(acc[m][n][r] + bv));
        }
    }
#pragma unroll
    for (int m = 0; m < 4; ++m) {
        u16x8 v = *(u16x8*)&Vs[(m * 16 + l15) * 40 + 8 * l4];
        *(u16x8*)(vimg + ((size_t)(b * 32 + pt) * 256 + o0 + m * 16 + l15) * 32 + 8 * l4) = v;
    }
}

// ---------------------------------------------------------------------------
// Kernel 3: flash attention, 32x32x16 MFMA, 64-row blocks, 4 waves =
// (2 row-groups) x (2 j-halves) with exact combine. Swapped QK (S[j][i]),
// lane-local softmax/rescale, in-register P via cvt_pkrtz+permlane32_swap,
// gll-staged XOR-swizzled K & V, lane-local maxpool epilogue.
// ---------------------------------------------------------------------------
#define SMEM_A 66560
__global__ __launch_bounds__(256, 2) void k_attn(const u16* __restrict__ qf,
                                                 const u16* __restrict__ vimg,
                                                 float* __restrict__ out) {
    __shared__ __align__(16) char smem[SMEM_A];
    u16* Kb = (u16*)smem;               // [2 jg][32][256] swz (32768 B)
    u16* Vb = (u16*)(smem + 32768);     // [2 jg][256][32] swz (32768 B)
    float* Mx = (float*)(smem + 65536); // [4][32]
    float* Lx = (float*)(smem + 66048); // [4][32]
    float* Ob = (float*)smem;           // reuse 64KB for combine

    int bid = blockIdx.x;
    int xcd = bid & 7, s0 = bid >> 3;
    int b = xcd * 4 + (s0 >> 4);
    int i0 = (s0 & 15) * 64;
    int t = threadIdx.x, wave = t >> 6, lane = t & 63;
    int rg = wave & 1, jg = wave >> 1;
    int l31 = lane & 31, lh = lane >> 5, l7 = lane & 7;
    const u16* qb = qf + (size_t)b * NN * CC;
    const u16* vtb = vimg + (size_t)b * (32 * 8192);

    // ---- prologue: stage Q rows i0..i0+63 into Kb (tile = 32-row half)
    {
        int Gb = wave * 512;
#pragma unroll
        for (int inst = 0; inst < 8; ++inst) {
            int G = Gb + inst * 64 + lane;
            int row = (G >> 5) & 31, g = G & 31, tile = G >> 10;
            gll16(qb + (size_t)(i0 + tile * 32 + row) * CC + ((g ^ (row & 7)) << 3),
                  Kb + (size_t)(Gb + inst * 64) * 8);
        }
    }
    __syncthreads();
    h16x8 qfr[16];
    {
        const u16* qB = Kb + rg * 8192 + l31 * 256;
#pragma unroll
        for (int ks = 0; ks < 16; ++ks)
            qfr[ks] = ldh8(qB + (((2 * ks + lh) ^ l7) << 3));
    }
    __syncthreads();
    // ---- stage K(it=0) and V(it=0): tile 0 -> jg0 (jt=0), tile 1 -> jg1 (jt=16)
    {
        int Gb = wave * 512;
#pragma unroll
        for (int inst = 0; inst < 8; ++inst) {
            int G = Gb + inst * 64 + lane;
            int row = (G >> 5) & 31, g = G & 31, tile = G >> 10;
            gll16(qb + (size_t)((tile * 16) * 32 + row) * CC + ((g ^ (row & 7)) << 3),
                  Kb + (size_t)(Gb + inst * 64) * 8);
        }
#pragma unroll
        for (int inst = 0; inst < 8; ++inst) {
            int G = Gb + inst * 64 + lane;
            int row = (G >> 2) & 255, gi = G & 3, tile = G >> 10;
            gll16(vtb + (size_t)(tile * 16) * 8192 + row * 32 + ((gi ^ ((row >> 1) & 3)) << 3),
                  Vb + (size_t)(Gb + inst * 64) * 8);
        }
    }
    __syncthreads();

    f32x16 oacc[8];
#pragma unroll
    for (int oc = 0; oc < 8; ++oc)
#pragma unroll
        for (int r = 0; r < 16; ++r) oacc[oc][r] = 0.f;
    float m = -INFINITY, l = 0.f;
    const u16* KbJ = Kb + jg * 8192;
    const u16* VbJ = Vb + jg * 8192;
    int l31s = (l31 >> 1) & 3;

    for (int it = 0; it < 16; ++it) {
        // QK^T swapped: S[j = A-rows][i = l31]
        f32x16 s;
#pragma unroll
        for (int r = 0; r < 16; ++r) s[r] = 0.f;
        __builtin_amdgcn_s_setprio(1);
#pragma unroll
        for (int ks = 0; ks < 16; ++ks) {
            h16x8 a = ldh8(KbJ + l31 * 256 + (((2 * ks + lh) ^ l7) << 3));
            s = mfma32(a, qfr[ks], s);
        }
        __builtin_amdgcn_s_setprio(0);
        __syncthreads();  // B1: all QK reads of Kb done
        if (it < 15) {    // async prefetch K(it+1); lands by B2
            int Gb = wave * 512;
#pragma unroll
            for (int inst = 0; inst < 8; ++inst) {
                int G = Gb + inst * 64 + lane;
                int row = (G >> 5) & 31, g = G & 31, tile = G >> 10;
                gll16(qb + (size_t)((tile * 16 + it + 1) * 32 + row) * CC +
                          ((g ^ (row & 7)) << 3),
                      Kb + (size_t)(Gb + inst * 64) * 8);
            }
        }
        // lane-local online softmax: 16 j-values for column i = l31
        float mx = s[0];
#pragma unroll
        for (int r = 1; r < 16; ++r) mx = fmaxf(mx, s[r]);
        mx = fmaxf(mx, __shfl_xor(mx, 32));
        if (__any(mx > m + THR)) {
            float mn = fmaxf(m, mx);
            float f = __expf(m - mn);
            m = mn;
            l *= f;
#pragma unroll
            for (int oc = 0; oc < 8; ++oc)
#pragma unroll
                for (int r = 0; r < 16; ++r) oacc[oc][r] *= f;
        }
        float p[16], rs = 0.f;
#pragma unroll
        for (int r = 0; r < 16; ++r) { p[r] = __expf(s[r] - m); rs += p[r]; }
        rs += __shfl_xor(rs, 32);
        l += rs;
        // pack P -> fp16 B-frags in-register (cvt_pkrtz + permlane32_swap)
        u32 pk0 = __builtin_bit_cast(u32, __builtin_amdgcn_cvt_pkrtz(p[0], p[1]));
        u32 pk1 = __builtin_bit_cast(u32, __builtin_amdgcn_cvt_pkrtz(p[2], p[3]));
        u32 pk2 = __builtin_bit_cast(u32, __builtin_amdgcn_cvt_pkrtz(p[4], p[5]));
        u32 pk3 = __builtin_bit_cast(u32, __builtin_amdgcn_cvt_pkrtz(p[6], p[7]));
        u32 pk4 = __builtin_bit_cast(u32, __builtin_amdgcn_cvt_pkrtz(p[8], p[9]));
        u32 pk5 = __builtin_bit_cast(u32, __builtin_amdgcn_cvt_pkrtz(p[10], p[11]));
        u32 pk6 = __builtin_bit_cast(u32, __builtin_amdgcn_cvt_pkrtz(p[12], p[13]));
        u32 pk7 = __builtin_bit_cast(u32, __builtin_amdgcn_cvt_pkrtz(p[14], p[15]));
        asm volatile("v_permlane32_swap_b32 %0, %1" : "+v"(pk0), "+v"(pk2));
        asm volatile("v_permlane32_swap_b32 %0, %1" : "+v"(pk1), "+v"(pk3));
        asm volatile("v_permlane32_swap_b32 %0, %1" : "+v"(pk4), "+v"(pk6));
        asm volatile("v_permlane32_swap_b32 %0, %1" : "+v"(pk5), "+v"(pk7));
        h16x8 pa0 = __builtin_bit_cast(h16x8, (u32x4v){pk0, pk1, pk2, pk3});
        h16x8 pa1 = __builtin_bit_cast(h16x8, (u32x4v){pk4, pk5, pk6, pk7});
        // PV: O[o][i] += V[o][j] P[j][i]
        __builtin_amdgcn_s_setprio(1);
#pragma unroll
        for (int oc = 0; oc < 8; ++oc) {
            h16x8 v0 = ldh8(VbJ + (oc * 32 + l31) * 32 + (((0 + lh) ^ l31s) << 3));
            h16x8 v1 = ldh8(VbJ + (oc * 32 + l31) * 32 + (((2 + lh) ^ l31s) << 3));
            oacc[oc] = mfma32(v0, pa0, oacc[oc]);
            oacc[oc] = mfma32(v1, pa1, oacc[oc]);
        }
        __builtin_amdgcn_s_setprio(0);
        __syncthreads();  // B2: PV reads done; K(it+1) drained
        if (it < 15) {    // async prefetch V(it+1); lands by next B1
            int Gb = wave * 512;
#pragma unroll
            for (int inst = 0; inst < 8; ++inst) {
                int G = Gb + inst * 64 + lane;
                int row = (G >> 2) & 255, gi = G & 3, tile = G >> 10;
                gll16(vtb + (size_t)(tile * 16 + it + 1) * 8192 + row * 32 +
                          ((gi ^ ((row >> 1) & 3)) << 3),
                      Vb + (size_t)(Gb + inst * 64) * 8);
            }
        }
    }

    // ---- combine j-halves (exact): partner wave = wave^2
    if (lane < 32) {
        Mx[wave * 32 + l31] = m;
        Lx[wave * 32 + l31] = l;
    }
    if (jg == 1) {  // write raw acc frags, conflict-free vector slots
#pragma unroll
        for (int oc = 0; oc < 8; ++oc)
#pragma unroll
            for (int q = 0; q < 4; ++q) {
                f32x4 v = (f32x4){oacc[oc][4 * q + 0], oacc[oc][4 * q + 1],
                                  oacc[oc][4 * q + 2], oacc[oc][4 * q + 3]};
                *(f32x4*)&Ob[(((rg * 8 + oc) * 4 + q) * 64 + lane) * 4] = v;
            }
    }
    __syncthreads();
    if (jg == 0) {
        int pidx = (wave ^ 2) * 32 + l31;
        float m2 = Mx[pidx], l2 = Lx[pidx];
        float ms = fmaxf(m, m2);
        float f0 = __expf(m - ms), f1 = __expf(m2 - ms);
        float inv = 1.f / (l * f0 + l2 * f1);
        f0 *= inv; f1 *= inv;
#pragma unroll
        for (int oc = 0; oc < 8; ++oc)
#pragma unroll
            for (int q = 0; q < 4; ++q) {
                f32x4 o1 = *(const f32x4*)&Ob[(((rg * 8 + oc) * 4 + q) * 64 + lane) * 4];
#pragma unroll
                for (int e = 0; e < 4; ++e)
                    oacc[oc][4 * q + e] = oacc[oc][4 * q + e] * f0 + o1[e] * f1;
            }
        // lane-local 2x2 maxpool + interleaved-reshape store.
        // lane holds i = l31 (position), o = oc*32 + (r&3)+8*(r>>2)+4*lh
        int I = i0 + rg * 32 + l31;
        float* ob = out + ((size_t)(b * 256 + (I >> 2)) * 16 + (I & 3) * 4) * 16;
#pragma unroll
        for (int pl = 0; pl < 4; ++pl) {
#pragma unroll
            for (int pwh = 0; pwh < 8; ++pwh) {
                int r0 = 2 * (pwh & 1) + 4 * (pwh >> 1);  // lane-invariant
                int oc0 = 2 * pl;
                float v = fmaxf(fmaxf(oacc[oc0][r0], oacc[oc0][r0 + 1]),
                                fmaxf(oacc[oc0 + 1][r0], oacc[oc0 + 1][r0 + 1]));
                int pw = (pwh & 1) + 4 * (pwh >> 1) + 2 * lh;
                ob[pl * 16 + pw] = v;
            }
        }
    }
}

// ---------------------------------------------------------------------------
extern "C" void kernel_launch(void* const* d_in, const int* in_sizes, int n_in,
                              void* d_out, int out_size, void* d_ws, size_t ws_size,
                              hipStream_t stream) {
    const float* x = (const float*)d_in[0];
    const float* w = (const float*)d_in[1];
    const float* bias = (const float*)d_in[2];
    float* out = (float*)d_out;
    u16* qf = (u16*)d_ws;                    // [32][1024][256] fp16
    u16* vimg = qf + (size_t)BB * NN * CC;   // [32][32][256][32] fp16
    u16* whf = vimg + (size_t)BB * NN * CC;  // fragment-major W
    k_split<<<2080, 256, 0, stream>>>(x, qf, w, whf);
    k_vgemm<<<1024, 256, 0, stream>>>(qf, whf, bias, vimg);
    k_attn<<<512, 256, 0, stream>>>(qf, vimg, out);
}

// Round 5
// 144.049 us; speedup vs baseline: 1.2002x; 1.2002x over previous
//
#include <hip/hip_runtime.h>
#include <math.h>

#define BB 32
#define CC 256
#define NN 1024
#define KSTR 256   // linear K-tile stride (gll16 requires contiguous dst; XOR swizzle instead of pad)
#define PSTR 40
#define THR 8.0f

typedef unsigned short u16;
typedef unsigned int u32;
typedef u16 u16x8 __attribute__((ext_vector_type(8)));
typedef _Float16 h16;
typedef h16 h16x8 __attribute__((ext_vector_type(8)));
typedef h16 h16x4 __attribute__((ext_vector_type(4)));
typedef float f32x4 __attribute__((ext_vector_type(4)));

__device__ __forceinline__ h16x8 ldh8(const u16* p) {
    return __builtin_bit_cast(h16x8, *(const u16x8*)p);
}
__device__ __forceinline__ f32x4 mfma16(h16x8 a, h16x8 b, f32x4 c) {
    return __builtin_amdgcn_mfma_f32_16x16x32_f16(a, b, c, 0, 0, 0);
}
// async global->LDS, 16B/lane: dst = wave-uniform base + lane*16 (linear)
__device__ __forceinline__ void gll16(const void* g, void* l) {
    __builtin_amdgcn_global_load_lds((const __attribute__((address_space(1))) u32*)g,
                                     (__attribute__((address_space(3))) u32*)l, 16, 0, 0);
}

// ---------------------------------------------------------------------------
// Kernel 0: W f32 [256][256] -> fragment-major fp16 Whf (A-frag slots).
// ---------------------------------------------------------------------------
__global__ __launch_bounds__(256) void k_wprep(const float* __restrict__ w,
                                               u16* __restrict__ whf) {
    int s = blockIdx.x * 256 + threadIdx.x;  // 8192 slots
    int ot = s >> 9, ks = (s >> 6) & 7, l = s & 63;
    const float* src = w + (size_t)(ot * 16 + (l & 15)) * CC + ks * 32 + 8 * (l >> 4);
    float4 a = *(const float4*)src;
    float4 c = *(const float4*)(src + 4);
    u16x8 o;
    o[0] = __builtin_bit_cast(u16, (h16)a.x); o[1] = __builtin_bit_cast(u16, (h16)a.y);
    o[2] = __builtin_bit_cast(u16, (h16)a.z); o[3] = __builtin_bit_cast(u16, (h16)a.w);
    o[4] = __builtin_bit_cast(u16, (h16)c.x); o[5] = __builtin_bit_cast(u16, (h16)c.y);
    o[6] = __builtin_bit_cast(u16, (h16)c.z); o[7] = __builtin_bit_cast(u16, (h16)c.w);
    *(u16x8*)(whf + (size_t)s * 8) = o;
}

// ---------------------------------------------------------------------------
// Kernel 1 (fused): per (b, 32-p tile): transpose x[b][c][p] f32 -> qf[b][p][c]
// fp16 AND compute V = W@X + b into fragment-major vf. 1024 blocks, 4/CU.
// x staged per 64-c chunk into fp32 LDS [32 p][68]; qf store + B-frags from it.
// vf[((b*32 + jt)*16 + of)*512 + lane*8 + e] = V[b][of*16+(l&15)][jt*32+8*(l>>4)+e]
// ---------------------------------------------------------------------------
__global__ __launch_bounds__(256, 4) void k_xform(const float* __restrict__ x,
                                                  const u16* __restrict__ whf,
                                                  const float* __restrict__ bias,
                                                  u16* __restrict__ qf,
                                                  u16* __restrict__ vf) {
    __shared__ __align__(16) float xs[32][68];  // 8704 B
    __shared__ __align__(16) u16 Vs[4][64 * 40];  // 20480 B
    int bid = blockIdx.x;
    int b = bid >> 5, pt = bid & 31;
    int t = threadIdx.x, wave = t >> 6, lane = t & 63;
    int l15 = lane & 15, l4 = lane >> 4;
    int p0 = pt * 32;

    f32x4 acc[4][2];
#pragma unroll
    for (int m = 0; m < 4; ++m)
#pragma unroll
        for (int n = 0; n < 2; ++n) acc[m][n] = (f32x4){0.f, 0.f, 0.f, 0.f};

    for (int cc = 0; cc < 4; ++cc) {
        // stage+transpose chunk: c rows cc*64..+63, p cols p0..p0+31
#pragma unroll
        for (int it = 0; it < 2; ++it) {
            int r = (t >> 3) + it * 32;      // c-local 0..63
            int pq = (t & 7) * 4;            // p-local
            float4 v = *(const float4*)(x + (size_t)(b * CC + cc * 64 + r) * NN + p0 + pq);
            xs[pq + 0][r] = v.x;
            xs[pq + 1][r] = v.y;
            xs[pq + 2][r] = v.z;
            xs[pq + 3][r] = v.w;
        }
        __syncthreads();
        // qf store: row p = t>>3 (0..31), c-seg cl = (t&7)*8 within chunk
        {
            int p = t >> 3, cl = (t & 7) * 8;
            u16x8 hv;
#pragma unroll
            for (int e = 0; e < 8; ++e)
                hv[e] = __builtin_bit_cast(u16, (h16)xs[p][cl + e]);
            *(u16x8*)(qf + (size_t)(b * NN + p0 + p) * CC + cc * 64 + cl) = hv;
        }
        // GEMM over this chunk's two k-steps
#pragma unroll
        for (int ksl = 0; ksl < 2; ++ksl) {
            int ks = cc * 2 + ksl;
            h16x8 afr[4], bfr[2];
#pragma unroll
            for (int m = 0; m < 4; ++m)
                afr[m] = ldh8(whf + (size_t)(((wave * 4 + m) * 8 + ks) * 64 + lane) * 8);
#pragma unroll
            for (int n = 0; n < 2; ++n) {
                const float* sp = &xs[n * 16 + l15][ksl * 32 + 8 * l4];
                f32x4 w0 = *(const f32x4*)sp;
                f32x4 w1 = *(const f32x4*)(sp + 4);
                h16x8 tv;
                tv[0] = (h16)w0[0]; tv[1] = (h16)w0[1]; tv[2] = (h16)w0[2]; tv[3] = (h16)w0[3];
                tv[4] = (h16)w1[0]; tv[5] = (h16)w1[1]; tv[6] = (h16)w1[2]; tv[7] = (h16)w1[3];
                bfr[n] = tv;
            }
#pragma unroll
            for (int m = 0; m < 4; ++m)
#pragma unroll
                for (int n = 0; n < 2; ++n) acc[m][n] = mfma16(afr[m], bfr[n], acc[m][n]);
        }
        __syncthreads();  // xs reused next chunk
    }

    // epilogue: bias + per-wave transpose -> frag-major vf (jt == pt)
    u16* Vsw = &Vs[wave][0];  // [64 o][40]
#pragma unroll
    for (int m = 0; m < 4; ++m) {
#pragma unroll
        for (int r = 0; r < 4; ++r) {
            int ol = m * 16 + 4 * l4 + r;
            float bv = bias[wave * 64 + ol];
#pragma unroll
            for (int n = 0; n < 2; ++n)
                Vsw[ol * 40 + n * 16 + l15] =
                    __builtin_bit_cast(u16, (h16)(acc[m][n][r] + bv));
        }
    }
#pragma unroll
    for (int m = 0; m < 4; ++m) {
        u16x8 v = *(u16x8*)&Vsw[(m * 16 + l15) * 40 + 8 * l4];
        *(u16x8*)(vf + (((size_t)(b * 32 + pt) * 16) + wave * 4 + m) * 512 + lane * 8) = v;
    }
}

// ---------------------------------------------------------------------------
// Kernel 2: flash attention (swapped-QK, lane-local softmax, defer-max).
// K double-buffered via global_load_lds (linear LDS + XOR granule swizzle,
// R4-verified); V coalesced from fragment-major vf; one barrier per jt.
// Block = (batch, 64 query rows), 4 waves x 16 rows.
// ---------------------------------------------------------------------------
#define SMEM_BYTES 38400
__global__ __launch_bounds__(256, 2) void k_attn(const u16* __restrict__ qf,
                                                 const u16* __restrict__ vf,
                                                 float* __restrict__ out) {
    __shared__ __align__(16) char smem[SMEM_BYTES];
    u16* Kt = (u16*)smem;                // 2 x [32][256] fp16 (32768 B)
    u16* Pt = (u16*)(smem + 32768);      // [4 waves][16][PSTR] (5120 B)
    float* Sc = (float*)(smem + 37888);  // [4 waves][16] broadcast scratch

    int bid = blockIdx.x;
    int xcd = bid & 7, s0 = bid >> 3;
    int b = xcd * 4 + (s0 >> 4);
    int i0 = (s0 & 15) * 64;
    int t = threadIdx.x, wave = t >> 6, lane = t & 63;
    int l15 = lane & 15, l4 = lane >> 4, l7 = lane & 7;
    int iw = i0 + wave * 16;

    const u16* qb = qf + (size_t)b * NN * CC;
    const u16* vfb = vf + (size_t)b * (32 * 16 * 512);

// stage K tile rows [J0,J0+32) into buffer BUF (async, swizzled source)
#define STAGE_K(J0, BUF)                                                        \
    {                                                                           \
        int Gb = wave * 4;                                                      \
        _Pragma("unroll") for (int inst = 0; inst < 4; ++inst) {                \
            int G = (Gb + inst) * 64 + lane;                                    \
            int row = G >> 5, g = G & 31;                                       \
            gll16(qb + (size_t)((J0) + row) * CC + ((g ^ (row & 7)) << 3),      \
                  Kt + (BUF) * 8192 + (size_t)(Gb + inst) * 512);               \
        }                                                                       \
    }

    // Q fragments in registers: lane holds query row iw+l15, k = ks*32+8*l4..
    h16x8 qfr[8];
#pragma unroll
    for (int ks = 0; ks < 8; ++ks)
        qfr[ks] = ldh8(qb + (size_t)(iw + l15) * CC + ks * 32 + 8 * l4);

    f32x4 oacc[16];
#pragma unroll
    for (int i = 0; i < 16; ++i) oacc[i] = (f32x4){0.f, 0.f, 0.f, 0.f};
    float m = -INFINITY, l = 0.f;

    STAGE_K(0, 0);
    __syncthreads();

    u16* Pw = Pt + wave * 16 * PSTR;
    float* Scw = Sc + wave * 16;

    for (int jt = 0; jt < 32; ++jt) {
        int cur = jt & 1;
        int j0 = jt * 32;

        // V fragments: coalesced b128 from frag-major vf (issued FIRST so the
        // compiler's vmcnt for V use leaves the gll prefetch in flight)
        u16x8 vfr[16];
#pragma unroll
        for (int of = 0; of < 16; ++of)
            vfr[of] = *(const u16x8*)(vfb + ((size_t)(jt * 16 + of) * 512 + lane * 8));

        if (jt < 31) STAGE_K(j0 + 32, cur ^ 1);  // async into other buffer

        // QK^T swapped: A = K rows (j), B = Q rows (i).
        const u16* KtC = Kt + cur * 8192 + l15 * KSTR;
        f32x4 s0v = (f32x4){0.f, 0.f, 0.f, 0.f};
        f32x4 s1v = (f32x4){0.f, 0.f, 0.f, 0.f};
#pragma unroll
        for (int ks = 0; ks < 8; ++ks) {
            int g0 = ((4 * ks + l4) ^ l7) << 3;
            h16x8 a0 = ldh8(KtC + g0);
            h16x8 a1 = ldh8(KtC + 16 * KSTR + g0);
            s0v = mfma16(a0, qfr[ks], s0v);
            s1v = mfma16(a1, qfr[ks], s1v);
        }

        // lane-local softmax for query i = l15 (8 scores per lane)
        float mx = fmaxf(fmaxf(fmaxf(s0v[0], s0v[1]), fmaxf(s0v[2], s0v[3])),
                         fmaxf(fmaxf(s1v[0], s1v[1]), fmaxf(s1v[2], s1v[3])));
        mx = fmaxf(mx, __shfl_xor(mx, 16));
        mx = fmaxf(mx, __shfl_xor(mx, 32));
        if (__any(mx > m + THR)) {  // defer-max
            float mnew = fmaxf(m, mx);
            float sc = __expf(m - mnew);
            m = mnew;
            l *= sc;
            Scw[l15] = sc;
            f32x4 s4 = *(f32x4*)&Scw[4 * l4];
#pragma unroll
            for (int of = 0; of < 16; ++of)
#pragma unroll
                for (int r = 0; r < 4; ++r) oacc[of][r] *= s4[r];
        }
        float p0 = __expf(s0v[0] - m), p1 = __expf(s0v[1] - m);
        float p2 = __expf(s0v[2] - m), p3 = __expf(s0v[3] - m);
        float p4 = __expf(s1v[0] - m), p5 = __expf(s1v[1] - m);
        float p6 = __expf(s1v[2] - m), p7 = __expf(s1v[3] - m);
        float rs = ((p0 + p1) + (p2 + p3)) + ((p4 + p5) + (p6 + p7));
        rs += __shfl_xor(rs, 16);
        rs += __shfl_xor(rs, 32);
        l += rs;

        // P -> fp16 -> per-wave LDS transpose -> A-frag
        h16x4 pk0 = {(h16)p0, (h16)p1, (h16)p2, (h16)p3};  // j = 4*l4+0..3
        h16x4 pk1 = {(h16)p4, (h16)p5, (h16)p6, (h16)p7};  // j = 16+4*l4..
        *(h16x4*)(Pw + l15 * PSTR + 4 * l4) = pk0;
        *(h16x4*)(Pw + l15 * PSTR + 16 + 4 * l4) = pk1;
        h16x8 pa = ldh8(Pw + l15 * PSTR + 8 * l4);

        // PV: O[i][o] += P[i][j] V[j][o]
#pragma unroll
        for (int of = 0; of < 16; ++of)
            oacc[of] = mfma16(pa, __builtin_bit_cast(h16x8, vfr[of]), oacc[of]);

        if (jt < 31) __syncthreads();  // drains gll prefetch; frees buf cur
    }

    // normalize: broadcast 1/l from i=l15 layout to row(4*l4+r) layout
    {
        float inv = 1.0f / l;
        Scw[l15] = inv;
        f32x4 inv4 = *(f32x4*)&Scw[4 * l4];
#pragma unroll
        for (int of = 0; of < 16; ++of)
#pragma unroll
            for (int r = 0; r < 4; ++r) oacc[of][r] *= inv4[r];
    }

    // Epilogue: 2-pass through LDS, interleaved reshape + 2x2 maxpool.
    // oacc: row i = 4*l4 + r (wave's 16), col o = of*16 + l15.
    float* Old = (float*)smem;  // [32][260]
#pragma unroll
    for (int half = 0; half < 2; ++half) {
        __syncthreads();
        if ((wave >> 1) == half) {
            int wrow = (wave & 1) * 16;
#pragma unroll
            for (int of = 0; of < 16; ++of)
#pragma unroll
                for (int r = 0; r < 4; ++r)
                    Old[(wrow + 4 * l4 + r) * 260 + of * 16 + l15] = oacc[of][r];
        }
        __syncthreads();
#pragma unroll
        for (int it = 0; it < 8; ++it) {
            int q = it * 16 + (t >> 4);
            int ill = q >> 2, pl = q & 3, pw = t & 15;
            const float* row = &Old[ill * 260];
            int ob = pl * 64 + pw * 2;
            float mx2 = fmaxf(fmaxf(row[ob], row[ob + 1]),
                              fmaxf(row[ob + 32], row[ob + 33]));
            int i = i0 + half * 32 + ill;
            out[(((size_t)b * CC + (i >> 2)) * 16 + (i & 3) * 4 + pl) * 16 + pw] = mx2;
        }
    }
}

// ---------------------------------------------------------------------------
extern "C" void kernel_launch(void* const* d_in, const int* in_sizes, int n_in,
                              void* d_out, int out_size, void* d_ws, size_t ws_size,
                              hipStream_t stream) {
    const float* x = (const float*)d_in[0];
    const float* w = (const float*)d_in[1];
    const float* bias = (const float*)d_in[2];
    float* out = (float*)d_out;
    u16* qf = (u16*)d_ws;                    // [32][1024][256] fp16
    u16* vf = qf + (size_t)BB * NN * CC;     // fragment-major V
    u16* whf = vf + (size_t)BB * NN * CC;    // fragment-major W
    k_wprep<<<32, 256, 0, stream>>>(w, whf);
    k_xform<<<1024, 256, 0, stream>>>(x, whf, bias, qf, vf);
    k_attn<<<512, 256, 0, stream>>>(qf, vf, out);
}